// Round 10
// baseline (383.913 us; speedup 1.0000x reference)
//
#include <hip/hip_runtime.h>
#include <hip/hip_fp16.h>
#include <math.h>

// FBP adjoint as dense f16 MFMA GEMM, FUSED producer-consumer (R19).
//   out[b,i0,i1,i2] = (1/A) * sum_{j,k} W[(i0,i2),(j,k)] * x[b,j,i1,k]
// C[M=1089, N=4224(i1*128+b)] = W[MxK] . Xt[NxK]^T, K=3993 padded to 4032.
// R19: pipelining failed 3x (R10 92, R12 89.6, R18 90.2 vs plain 70.9) ->
// gemm inner loop FROZEN at R13-exact. Non-gemm ~107us is invariant across
// 5 prep variants; disambiguate "prep is real work" vs "fixed overhead" by
// fusing prep+gemm in ONE kernel: 1188 blocks first drain a work-stealing
// queue of 5376 prep chunks (R13 bodies; stealing = deadlock-free under
// undefined dispatch order), post per-tile ready counters (release fence +
// device atomics, G16), then each block spin-waits on its own tileM/tileN
// counters and runs the frozen K-loop. Early tiles start MFMA while late
// prep chunks still run -> prep hides under gemm. Same-panel blocks unblock
// together -> preserves lockstep L2 sharing (R17 lesson). K order unchanged
// -> bit-identical absmax.

#define PDIM 33
#define PP   1089
#define A_   121
#define K_   3993
#define KP   4032
#define MP   1152            // padded M (18*64)
#define MT2  18              // M tiles (64)
#define NT2  66              // N tiles (64) = 33 i1 * 2 b-halves
#define NWG  1188            // MT2*NT2
#define OUTB 35937           // 33*33*33
#define NXCH 4224            // Xt chunks (rows)
#define NCHUNK (NXCH + MP)   // + 1152 W chunks = 5376
#define NGRP 84              // 66 Xt groups + 18 W groups

typedef _Float16 f16x8 __attribute__((ext_vector_type(8)));
typedef float    f32x4 __attribute__((ext_vector_type(4)));
typedef _Float16 h2v   __attribute__((ext_vector_type(2)));

typedef __attribute__((address_space(1))) const unsigned int* gp_t;
typedef __attribute__((address_space(3))) unsigned int*       lp_t;

// ---------------- fused prep + gemm ----------------

__global__ __launch_bounds__(256)
void fused_kernel(const float* __restrict__ x, const float* __restrict__ angles,
                  __half* __restrict__ W, __half* __restrict__ Xt,
                  int* __restrict__ flags, float* __restrict__ out, float invA)
{
    __shared__ _Float16 As[64 * 64];     // 8 KB, chunk-swizzled
    __shared__ _Float16 Bs[64 * 64];     // 8 KB
    __shared__ int chunk_s;
    __shared__ int lcnt[NGRP];

    int* nextp = flags;                  // [0] = work-steal cursor
    int* cnt   = flags + 1;              // [1..84] = per-group done counters

    const int t = threadIdx.x;
    for (int g = t; g < NGRP; g += 256) lcnt[g] = 0;

    // ================= phase 1: drain prep queue (work stealing) ==========
    for (;;) {
        __syncthreads();                 // chunk_s reuse + prior chunk done
        if (t == 0) chunk_s = atomicAdd(nextp, 1);
        __syncthreads();
        const int c = chunk_s;
        if (c >= NCHUNK) break;

        if (c < NXCH) {
            // ---- Xt row n=(i1*128+b): x[b,:,i1,:] flat (j,k) fp16, K-pad 0.
            const int n  = c;
            const int i1 = n >> 7;
            const int b  = n & 127;
            const float* src = x + (size_t)b * (A_ * PP) + (size_t)i1 * PDIM;
            unsigned int* dst = (unsigned int*)(Xt + (size_t)n * KP);
            for (int e = t; e < KP / 2; e += 256) {
                int kk0 = 2 * e, kk1 = 2 * e + 1;
                float v0 = 0.0f, v1 = 0.0f;
                if (kk0 < K_) {
                    int j = kk0 / PDIM, k = kk0 - j * PDIM;
                    v0 = src[(size_t)j * PP + k];
                }
                if (kk1 < K_) {
                    int j = kk1 / PDIM, k = kk1 - j * PDIM;
                    v1 = src[(size_t)j * PP + k];
                }
                dst[e] = __builtin_bit_cast(unsigned int,
                             __builtin_amdgcn_cvt_pkrtz(v0, v1));
            }
        } else {
            // ---- W row n: zero-fill (int4) then scatter 2 taps per angle.
            const int n = c - NXCH;              // 0..1151
            __half* row = W + (size_t)n * KP;    // 8064 B, 16B-aligned
            int4 zz = make_int4(0, 0, 0, 0);
            for (int e = t; e < KP / 8; e += 256)
                ((int4*)row)[e] = zz;
            __syncthreads();
            if (n < PP && t < A_) {
                const int j  = t;
                const int i0 = n / PDIM;
                const int i2 = n - i0 * PDIM;
                float s, cc;
                sincosf(angles[j], &s, &cc);
                float ix = fmaf((float)(i2 - 16), cc,
                                fmaf((float)(i0 - 16), s, 16.0f));
                float fl = floorf(ix);
                int   k0 = (int)fl;
                float w1 = ix - fl;
                float w0 = 1.0f - w1;
                __half* seg = row + j * PDIM;
                if (k0 >= 0     && k0 < PDIM)     seg[k0]     = __float2half_rn(w0);
                if (k0 + 1 >= 0 && k0 + 1 < PDIM) seg[k0 + 1] = __float2half_rn(w1);
            }
        }
        if (t == 0)
            ++lcnt[c < NXCH ? (c >> 6) : 66 + ((c - NXCH) >> 6)];
    }

    // Publish completions: all block stores -> device fence -> counters.
    __syncthreads();
    if (t == 0) {
        __threadfence();
        for (int g = 0; g < NGRP; ++g)
            if (lcnt[g]) atomicAdd(&cnt[g], lcnt[g]);
    }

    // ================= phase 2: gemm (R13-exact, frozen) ==================
    // XCD-aware bijective remap (blk%8 = XCD; nwg=1188: q=148,r=4)
    const int b0  = blockIdx.x;
    const int xcd = b0 & 7;
    const int pos = b0 >> 3;
    const int d   = (xcd < 4) ? xcd * 149 + pos
                              : 596 + (xcd - 4) * 148 + pos;
    int tileM, tileN;
    if (d < 324) {                       // chunks 0,1: 9 panels each
        int c = d / 162, l = d - c * 162;
        tileM = l / 9;
        tileN = c * 9 + (l - tileM * 9);
    } else {                             // chunks 2..7: 8 panels each
        int dd = d - 324;
        int c = dd / 144, l = dd - c * 144;
        tileM = l >> 3;
        tileN = 18 + c * 8 + (l & 7);
    }

    // Wait for this tile's W rows and Xt rows (acquire).
    if (t == 0) {
        while (__hip_atomic_load(&cnt[66 + tileM], __ATOMIC_ACQUIRE,
                                 __HIP_MEMORY_SCOPE_AGENT) < 64)
            __builtin_amdgcn_s_sleep(2);
        while (__hip_atomic_load(&cnt[tileN], __ATOMIC_ACQUIRE,
                                 __HIP_MEMORY_SCOPE_AGENT) < 64)
            __builtin_amdgcn_s_sleep(2);
        __threadfence();
    }
    __syncthreads();

    const int lane  = t & 63;
    const int wave  = t >> 6;
    const int warpM = wave >> 1;
    const int warpN = wave & 1;
    const int quad  = lane >> 4;
    const int l15   = lane & 15;

    f32x4 acc[2][2] = {};

    const __half* Ab = W  + (size_t)(tileM * 64) * KP;
    const __half* Bb = Xt + (size_t)(tileN * 64) * KP;

    // Staging chunk geometry: chunk cidx (0..511) = 16B = (row=cidx>>3,
    // seg=cidx&7). Global k-seg fetched = seg ^ (row&7); LDS dest linear.
    int srow[2], ssego[2];
#pragma unroll
    for (int i = 0; i < 2; ++i) {
        int cidx = t + i * 256;
        int row  = cidx >> 3;
        int seg  = cidx & 7;
        srow[i]  = row;
        ssego[i] = (seg ^ (row & 7)) * 8;   // halves offset within K-slice
    }

    // Frag-read addresses (halves): row r, k-seg ks -> r*64 + (ks^(r&7))*8
    int arow[2], brow[2];
#pragma unroll
    for (int s = 0; s < 2; ++s) {
        arow[s] = warpM * 32 + s * 16 + l15;
        brow[s] = warpN * 32 + s * 16 + l15;
    }

    for (int kb = 0; kb < KP; kb += 64) {
        __syncthreads();
#pragma unroll
        for (int i = 0; i < 2; ++i) {
            const __half* ga = Ab + (size_t)srow[i] * KP + kb + ssego[i];
            const __half* gb = Bb + (size_t)srow[i] * KP + kb + ssego[i];
            __builtin_amdgcn_global_load_lds((gp_t)(const void*)ga,
                (lp_t)(void*)&As[(t + i * 256) * 8], 16, 0, 0);
            __builtin_amdgcn_global_load_lds((gp_t)(const void*)gb,
                (lp_t)(void*)&Bs[(t + i * 256) * 8], 16, 0, 0);
        }
        __syncthreads();

        f16x8 af[2][2], bf[2][2];
#pragma unroll
        for (int h = 0; h < 2; ++h) {
#pragma unroll
            for (int s = 0; s < 2; ++s) {
                int ks = h * 4 + quad;
                af[h][s] = *(const f16x8*)&As[arow[s] * 64 + ((ks ^ (arow[s] & 7)) * 8)];
                bf[h][s] = *(const f16x8*)&Bs[brow[s] * 64 + ((ks ^ (brow[s] & 7)) * 8)];
            }
        }
#pragma unroll
        for (int h = 0; h < 2; ++h)
#pragma unroll
            for (int ms = 0; ms < 2; ++ms)
#pragma unroll
                for (int ns = 0; ns < 2; ++ns)
                    acc[ms][ns] = __builtin_amdgcn_mfma_f32_16x16x32_f16(
                        af[h][ms], bf[h][ns], acc[ms][ns], 0, 0, 0);
    }

    // Epilogue: C row m=(i0,i2), col nglob=(i1*128+b); out[b,i0,i1,i2].
#pragma unroll
    for (int ns = 0; ns < 2; ++ns) {
        int nglob = tileN * 64 + warpN * 32 + ns * 16 + l15;
        int i1 = nglob >> 7;
        int b  = nglob & 127;
        float* ob = out + (size_t)b * OUTB + (size_t)i1 * PDIM;
#pragma unroll
        for (int ms = 0; ms < 2; ++ms) {
#pragma unroll
            for (int r = 0; r < 4; ++r) {
                int m = tileM * 64 + warpM * 32 + ms * 16 + quad * 4 + r;
                if (m < PP) {
                    int i0 = m / PDIM;
                    int i2 = m - i0 * PDIM;
                    ob[(size_t)i0 * PP + i2] = acc[ms][ns][r] * invA;
                }
            }
        }
    }
}

// ---------------- fallback (R6, proven ~151 us) ----------------

#define ROWW 47
#define PADL 7
#define BLK  384
#define NV   3
#define GRID 1280

#if defined(__has_builtin)
#if __has_builtin(__builtin_amdgcn_fractf)
#define FRACTF(x) __builtin_amdgcn_fractf(x)
#endif
#endif
#ifndef FRACTF
#define FRACTF(x) ((x) - floorf(x))
#endif

__device__ __forceinline__ float fdot2u(unsigned int a, unsigned int b, float c)
{
    return __builtin_amdgcn_fdot2(__builtin_bit_cast(h2v, a),
                                  __builtin_bit_cast(h2v, b), c, false);
}

__global__ __launch_bounds__(BLK)
void fbp_adjoint_kernel(const float* __restrict__ x,
                        const float* __restrict__ angles,
                        float* __restrict__ out,
                        int nslice, float invA)
{
    __shared__ unsigned int dr[A_ * ROWW];
    __shared__ float2       cs_lds[A_];

    const int t = threadIdx.x;
    for (int j = t; j < A_; j += BLK) {
        float s, c;
        sincosf(angles[j], &s, &c);
        cs_lds[j] = make_float2(c, s);
    }

    float u0[NV], u2[NV];
#pragma unroll
    for (int nn = 0; nn < NV; ++nn) {
        int n  = t + nn * BLK;
        int nc = (n < PP) ? n : (PP - 1);
        int q0 = nc / PDIM;
        int q2 = nc - q0 * PDIM;
        u0[nn] = (float)(q0 - 16);
        u2[nn] = (float)(q2 - 16);
    }

    for (int slice = blockIdx.x; slice < nslice; slice += GRID) {
        if (slice != (int)blockIdx.x) __syncthreads();
        const int hb = slice / PDIM;
        const int i1 = slice - hb * PDIM;
        const int b0 = 2 * hb;
        const float* r0 = x + (size_t)b0 * (A_ * PP) + (size_t)i1 * PDIM;
        const float* r1 = r0 + (size_t)(A_ * PP);
        for (int e = t; e < A_ * ROWW; e += BLK) {
            int j = e / ROWW;
            int p = e - j * ROWW;
            int k = p - PADL;
            float f0 = 0.0f, f1 = 0.0f;
            if (k >= 0 && k < PDIM) {
                size_t o = (size_t)j * PP + k;
                f0 = r0[o];
                f1 = r1[o];
            }
            dr[e] = __builtin_bit_cast(unsigned int,
                        __halves2half2(__float2half_rn(f0), __float2half_rn(f1)));
        }
        __syncthreads();

        float a0[NV] = {0.0f, 0.0f, 0.0f};
        float a1[NV] = {0.0f, 0.0f, 0.0f};
#pragma unroll 2
        for (int j = 0; j < A_; ++j) {
            float2 cj = cs_lds[j];
            const unsigned int* base = &dr[j * ROWW];
#pragma unroll
            for (int nn = 0; nn < NV; ++nn) {
                float ixp = fmaf(u2[nn], cj.x, fmaf(u0[nn], cj.y, 23.0f));
                int   kp  = (int)ixp;
                float w1  = FRACTF(ixp);
                unsigned int wp = __builtin_bit_cast(unsigned int,
                                    __builtin_amdgcn_cvt_pkrtz(1.0f - w1, w1));
                unsigned int d0 = base[kp];
                unsigned int d1 = base[kp + 1];
                unsigned int p0 = __builtin_amdgcn_perm(d1, d0, 0x05040100u);
                unsigned int p1 = __builtin_amdgcn_perm(d1, d0, 0x07060302u);
                a0[nn] = fdot2u(p0, wp, a0[nn]);
                a1[nn] = fdot2u(p1, wp, a1[nn]);
            }
        }

        float* ob0 = out + (size_t)b0 * OUTB + (size_t)i1 * PDIM;
        float* ob1 = ob0 + (size_t)OUTB;
#pragma unroll
        for (int nn = 0; nn < NV; ++nn) {
            int n = t + nn * BLK;
            if (n < PP) {
                int q0 = n / PDIM;
                int q2 = n - q0 * PDIM;
                size_t o = (size_t)q0 * PP + q2;
                ob0[o] = a0[nn] * invA;
                ob1[o] = a1[nn] * invA;
            }
        }
    }
}

// ---------------- launch ----------------

extern "C" void kernel_launch(void* const* d_in, const int* in_sizes, int n_in,
                              void* d_out, int out_size, void* d_ws, size_t ws_size,
                              hipStream_t stream)
{
    const float* x      = (const float*)d_in[0];
    const float* angles = (const float*)d_in[1];
    float* out          = (float*)d_out;

    const int A = in_sizes[1];                    // 121
    const int B = in_sizes[0] / (A * PP);         // 128
    const float invA = 1.0f / (float)A;

    const size_t wBytes  = (size_t)MP * KP * sizeof(__half);         // 9.29 MB
    const size_t xtBytes = (size_t)(PDIM * B) * KP * sizeof(__half); // 34.1 MB
    const size_t fBytes  = (size_t)(1 + NGRP) * sizeof(int);         // 340 B

    if (ws_size >= wBytes + xtBytes + fBytes && A == A_ && B == 128) {
        __half* W  = (__half*)d_ws;
        __half* Xt = (__half*)((char*)d_ws + wBytes);
        int* flags = (int*)((char*)d_ws + wBytes + xtBytes);
        hipMemsetAsync(flags, 0, fBytes, stream);
        fused_kernel<<<NWG, 256, 0, stream>>>(x, angles, W, Xt, flags,
                                              out, invA);
    } else {
        const int nslice = (B / 2) * PDIM;
        dim3 grid(GRID < nslice ? GRID : nslice);
        fbp_adjoint_kernel<<<grid, BLK, 0, stream>>>(x, angles, out,
                                                     nslice, invA);
    }
}

// Round 11
// 182.801 us; speedup vs baseline: 2.1002x; 2.1002x over previous
//
#include <hip/hip_runtime.h>
#include <hip/hip_fp16.h>
#include <math.h>

// FBP adjoint as dense f16 MFMA GEMM.
//   out[b,i0,i1,i2] = (1/A) * sum_{j,k} W[(i0,i2),(j,k)] * x[b,j,i1,k]
// C[M=1089, N=4224(i1*128+b)] = W[MxK] . Xt[NxK]^T, K=3993 padded to 4096.
// R20: R19's fused work-steal kernel serialized on its single global cursor
// (~6.5k same-address atomics ~= 300us; MfmaUtil 5%) -> fusion dead, back
// to two dispatches. Ledger re-audit: R12 (BK=128) regressed with FETCH
// 220MB *pre-remap* (220/2.7TB/s = 81us ~= its 89.6) -> its failure was
// traffic, not BK. BK=128 x XCD-remap never tested. Per-CU model: step =
// LDS 48KB (32KB frag reads + 16KB staging) ~380clk vs 363clk MFMA at 2.8
// blocks -> ~34% LDS-side ceiling; gap to 21.6% = 63 vmcnt(0) drains.
// BK=128 halves drains, doubles in-flight loads/drain, same LDS/MAC, same
// FETCH; LDS 32KB = 5 blocks/CU >= grid 4.64. Compose R12 gemm body
// (numerics proven) + R13 remap + prep at KP=4096.

#define PDIM 33
#define PP   1089
#define A_   121
#define K_   3993
#define KP   4096            // padded K (32*128)
#define BK   128             // K-step
#define MP   1152            // padded M (18*64)
#define MT2  18              // M tiles (64)
#define NT2  66              // N tiles (64) = 33 i1 * 2 b-halves
#define NWG  1188            // MT2*NT2
#define OUTB 35937           // 33*33*33

typedef _Float16 f16x8 __attribute__((ext_vector_type(8)));
typedef float    f32x4 __attribute__((ext_vector_type(4)));
typedef _Float16 h2v   __attribute__((ext_vector_type(2)));

typedef __attribute__((address_space(1))) const unsigned int* gp_t;
typedef __attribute__((address_space(3))) unsigned int*       lp_t;

// ---------------- fused prep: Xt pack + W fill (R13 bodies, KP=4096) ------

__global__ __launch_bounds__(256)
void prep_kernel(const float* __restrict__ x, const float* __restrict__ angles,
                 __half* __restrict__ Xt, __half* __restrict__ W)
{
    const int blk = blockIdx.x;
    const int t   = threadIdx.x;

    if (blk < PDIM * 128) {
        // ---- Xt row n=(i1*128+b): x[b,:,i1,:] flattened (j,k) fp16, K-pad 0.
        const int n  = blk;
        const int i1 = n >> 7;
        const int b  = n & 127;
        const float* src = x + (size_t)b * (A_ * PP) + (size_t)i1 * PDIM;
        unsigned int* dst = (unsigned int*)(Xt + (size_t)n * KP);
        for (int e = t; e < KP / 2; e += 256) {
            int kk0 = 2 * e, kk1 = 2 * e + 1;
            float v0 = 0.0f, v1 = 0.0f;
            if (kk0 < K_) {
                int j = kk0 / PDIM, k = kk0 - j * PDIM;
                v0 = src[(size_t)j * PP + k];
            }
            if (kk1 < K_) {
                int j = kk1 / PDIM, k = kk1 - j * PDIM;
                v1 = src[(size_t)j * PP + k];
            }
            dst[e] = __builtin_bit_cast(unsigned int,
                         __builtin_amdgcn_cvt_pkrtz(v0, v1));
        }
    } else {
        // ---- W row n: zero-fill (int4) then scatter the 2 bilinear taps/angle.
        const int n = blk - PDIM * 128;      // 0..1151
        __half* row = W + (size_t)n * KP;    // 8192 B, 16B-aligned
        int4 zz = make_int4(0, 0, 0, 0);
        for (int e = t; e < KP / 8; e += 256)
            ((int4*)row)[e] = zz;
        __syncthreads();
        if (n >= PP || t >= A_) return;
        const int j  = t;
        const int i0 = n / PDIM;
        const int i2 = n - i0 * PDIM;
        float s, c;
        sincosf(angles[j], &s, &c);
        float ix = fmaf((float)(i2 - 16), c, fmaf((float)(i0 - 16), s, 16.0f));
        float fl = floorf(ix);
        int   k0 = (int)fl;
        float w1 = ix - fl;
        float w0 = 1.0f - w1;
        __half* seg = row + j * PDIM;
        if (k0 >= 0     && k0 < PDIM)     seg[k0]     = __float2half_rn(w0);
        if (k0 + 1 >= 0 && k0 + 1 < PDIM) seg[k0 + 1] = __float2half_rn(w1);
    }
}

// GEMM: C = W . Xt^T, 64x64 tile, BK=128, 4 waves (2x2), 32x32 per wave.
// R12 inner body (proven numerics) + R13 XCD-chunked mapping. 32 K-steps.
__global__ __launch_bounds__(256)
void gemm_kernel(const __half* __restrict__ W, const __half* __restrict__ Xt,
                 float* __restrict__ out, float invA)
{
    __shared__ _Float16 As[64 * BK];     // 16 KB, chunk-swizzled
    __shared__ _Float16 Bs[64 * BK];     // 16 KB

    // ---- XCD-aware bijective remap (blk%8 = XCD; nwg=1188: q=148,r=4) ----
    const int b0  = blockIdx.x;
    const int xcd = b0 & 7;
    const int pos = b0 >> 3;
    const int d   = (xcd < 4) ? xcd * 149 + pos
                              : 596 + (xcd - 4) * 148 + pos;
    int tileM, tileN;
    if (d < 324) {                       // chunks 0,1: 9 panels each
        int c = d / 162, l = d - c * 162;
        tileM = l / 9;
        tileN = c * 9 + (l - tileM * 9);
    } else {                             // chunks 2..7: 8 panels each
        int dd = d - 324;
        int c = dd / 144, l = dd - c * 144;
        tileM = l >> 3;
        tileN = 18 + c * 8 + (l & 7);
    }

    const int t     = threadIdx.x;
    const int lane  = t & 63;
    const int wave  = t >> 6;
    const int warpM = wave >> 1;
    const int warpN = wave & 1;
    const int quad  = lane >> 4;
    const int l15   = lane & 15;

    f32x4 acc[2][2] = {};

    const __half* Ab = W  + (size_t)(tileM * 64) * KP;
    const __half* Bb = Xt + (size_t)(tileN * 64) * KP;

    // Staging chunk geometry: chunk cidx (0..1023) = 16B = (row=cidx>>4,
    // seg=cidx&15). Global k-seg fetched = seg ^ (row&15); LDS dest linear.
    int srow[4], ssego[4];
#pragma unroll
    for (int i = 0; i < 4; ++i) {
        int cidx = t + i * 256;
        int row  = cidx >> 4;
        int seg  = cidx & 15;
        srow[i]  = row;
        ssego[i] = (seg ^ (row & 15)) * 8;  // halves offset within K-slice
    }

    // Frag-read rows: row r, k-seg ks -> r*BK + (ks^(r&15))*8
    int arow[2], brow[2];
#pragma unroll
    for (int s = 0; s < 2; ++s) {
        arow[s] = warpM * 32 + s * 16 + l15;
        brow[s] = warpN * 32 + s * 16 + l15;
    }

    for (int kb = 0; kb < KP; kb += BK) {
        __syncthreads();
#pragma unroll
        for (int i = 0; i < 4; ++i) {
            const __half* ga = Ab + (size_t)srow[i] * KP + kb + ssego[i];
            const __half* gb = Bb + (size_t)srow[i] * KP + kb + ssego[i];
            __builtin_amdgcn_global_load_lds((gp_t)(const void*)ga,
                (lp_t)(void*)&As[(t + i * 256) * 8], 16, 0, 0);
            __builtin_amdgcn_global_load_lds((gp_t)(const void*)gb,
                (lp_t)(void*)&Bs[(t + i * 256) * 8], 16, 0, 0);
        }
        __syncthreads();

        f16x8 af[4][2], bf[4][2];
#pragma unroll
        for (int h = 0; h < 4; ++h) {
#pragma unroll
            for (int s = 0; s < 2; ++s) {
                int ks = h * 4 + quad;
                af[h][s] = *(const f16x8*)
                    &As[arow[s] * BK + ((ks ^ (arow[s] & 15)) * 8)];
                bf[h][s] = *(const f16x8*)
                    &Bs[brow[s] * BK + ((ks ^ (brow[s] & 15)) * 8)];
            }
        }
#pragma unroll
        for (int h = 0; h < 4; ++h)
#pragma unroll
            for (int ms = 0; ms < 2; ++ms)
#pragma unroll
                for (int ns = 0; ns < 2; ++ns)
                    acc[ms][ns] = __builtin_amdgcn_mfma_f32_16x16x32_f16(
                        af[h][ms], bf[h][ns], acc[ms][ns], 0, 0, 0);
    }

    // Epilogue: C row m=(i0,i2), col nglob=(i1*128+b); out[b,i0,i1,i2].
#pragma unroll
    for (int ns = 0; ns < 2; ++ns) {
        int nglob = tileN * 64 + warpN * 32 + ns * 16 + l15;
        int i1 = nglob >> 7;
        int b  = nglob & 127;
        float* ob = out + (size_t)b * OUTB + (size_t)i1 * PDIM;
#pragma unroll
        for (int ms = 0; ms < 2; ++ms) {
#pragma unroll
            for (int r = 0; r < 4; ++r) {
                int m = tileM * 64 + warpM * 32 + ms * 16 + quad * 4 + r;
                if (m < PP) {
                    int i0 = m / PDIM;
                    int i2 = m - i0 * PDIM;
                    ob[(size_t)i0 * PP + i2] = acc[ms][ns][r] * invA;
                }
            }
        }
    }
}

// ---------------- fallback (R6, proven ~151 us) ----------------

#define ROWW 47
#define PADL 7
#define BLK  384
#define NV   3
#define GRID 1280

#if defined(__has_builtin)
#if __has_builtin(__builtin_amdgcn_fractf)
#define FRACTF(x) __builtin_amdgcn_fractf(x)
#endif
#endif
#ifndef FRACTF
#define FRACTF(x) ((x) - floorf(x))
#endif

__device__ __forceinline__ float fdot2u(unsigned int a, unsigned int b, float c)
{
    return __builtin_amdgcn_fdot2(__builtin_bit_cast(h2v, a),
                                  __builtin_bit_cast(h2v, b), c, false);
}

__global__ __launch_bounds__(BLK)
void fbp_adjoint_kernel(const float* __restrict__ x,
                        const float* __restrict__ angles,
                        float* __restrict__ out,
                        int nslice, float invA)
{
    __shared__ unsigned int dr[A_ * ROWW];
    __shared__ float2       cs_lds[A_];

    const int t = threadIdx.x;
    for (int j = t; j < A_; j += BLK) {
        float s, c;
        sincosf(angles[j], &s, &c);
        cs_lds[j] = make_float2(c, s);
    }

    float u0[NV], u2[NV];
#pragma unroll
    for (int nn = 0; nn < NV; ++nn) {
        int n  = t + nn * BLK;
        int nc = (n < PP) ? n : (PP - 1);
        int q0 = nc / PDIM;
        int q2 = nc - q0 * PDIM;
        u0[nn] = (float)(q0 - 16);
        u2[nn] = (float)(q2 - 16);
    }

    for (int slice = blockIdx.x; slice < nslice; slice += GRID) {
        if (slice != (int)blockIdx.x) __syncthreads();
        const int hb = slice / PDIM;
        const int i1 = slice - hb * PDIM;
        const int b0 = 2 * hb;
        const float* r0 = x + (size_t)b0 * (A_ * PP) + (size_t)i1 * PDIM;
        const float* r1 = r0 + (size_t)(A_ * PP);
        for (int e = t; e < A_ * ROWW; e += BLK) {
            int j = e / ROWW;
            int p = e - j * ROWW;
            int k = p - PADL;
            float f0 = 0.0f, f1 = 0.0f;
            if (k >= 0 && k < PDIM) {
                size_t o = (size_t)j * PP + k;
                f0 = r0[o];
                f1 = r1[o];
            }
            dr[e] = __builtin_bit_cast(unsigned int,
                        __halves2half2(__float2half_rn(f0), __float2half_rn(f1)));
        }
        __syncthreads();

        float a0[NV] = {0.0f, 0.0f, 0.0f};
        float a1[NV] = {0.0f, 0.0f, 0.0f};
#pragma unroll 2
        for (int j = 0; j < A_; ++j) {
            float2 cj = cs_lds[j];
            const unsigned int* base = &dr[j * ROWW];
#pragma unroll
            for (int nn = 0; nn < NV; ++nn) {
                float ixp = fmaf(u2[nn], cj.x, fmaf(u0[nn], cj.y, 23.0f));
                int   kp  = (int)ixp;
                float w1  = FRACTF(ixp);
                unsigned int wp = __builtin_bit_cast(unsigned int,
                                    __builtin_amdgcn_cvt_pkrtz(1.0f - w1, w1));
                unsigned int d0 = base[kp];
                unsigned int d1 = base[kp + 1];
                unsigned int p0 = __builtin_amdgcn_perm(d1, d0, 0x05040100u);
                unsigned int p1 = __builtin_amdgcn_perm(d1, d0, 0x07060302u);
                a0[nn] = fdot2u(p0, wp, a0[nn]);
                a1[nn] = fdot2u(p1, wp, a1[nn]);
            }
        }

        float* ob0 = out + (size_t)b0 * OUTB + (size_t)i1 * PDIM;
        float* ob1 = ob0 + (size_t)OUTB;
#pragma unroll
        for (int nn = 0; nn < NV; ++nn) {
            int n = t + nn * BLK;
            if (n < PP) {
                int q0 = n / PDIM;
                int q2 = n - q0 * PDIM;
                size_t o = (size_t)q0 * PP + q2;
                ob0[o] = a0[nn] * invA;
                ob1[o] = a1[nn] * invA;
            }
        }
    }
}

// ---------------- launch ----------------

extern "C" void kernel_launch(void* const* d_in, const int* in_sizes, int n_in,
                              void* d_out, int out_size, void* d_ws, size_t ws_size,
                              hipStream_t stream)
{
    const float* x      = (const float*)d_in[0];
    const float* angles = (const float*)d_in[1];
    float* out          = (float*)d_out;

    const int A = in_sizes[1];                    // 121
    const int B = in_sizes[0] / (A * PP);         // 128
    const float invA = 1.0f / (float)A;

    const size_t wBytes  = (size_t)MP * KP * sizeof(__half);         // 9.44 MB
    const size_t xtBytes = (size_t)(PDIM * B) * KP * sizeof(__half); // 34.6 MB

    if (ws_size >= wBytes + xtBytes && A == A_ && B == 128) {
        __half* W  = (__half*)d_ws;
        __half* Xt = (__half*)((char*)d_ws + wBytes);
        prep_kernel<<<PDIM * B + MP, 256, 0, stream>>>(x, angles, Xt, W);
        gemm_kernel<<<NWG, 256, 0, stream>>>(W, Xt, out, invA);
    } else {
        const int nslice = (B / 2) * PDIM;
        dim3 grid(GRID < nslice ? GRID : nslice);
        fbp_adjoint_kernel<<<grid, BLK, 0, stream>>>(x, angles, out,
                                                     nslice, invA);
    }
}

// Round 12
// 176.806 us; speedup vs baseline: 2.1714x; 1.0339x over previous
//
#include <hip/hip_runtime.h>
#include <hip/hip_fp16.h>
#include <math.h>

// FBP adjoint as dense f16 MFMA GEMM.
//   out[b,i0,i1,i2] = (1/A) * sum_{j,k} W[(i0,i2),(j,k)] * x[b,j,i1,k]
// C[M=1089, N=4224(i1*128+b)] = W[MxK] . Xt[NxK]^T, K=3993 padded to 4032.
// R21 = REVERT to R13-exact (measured best: 178.2us total; gemm 70.9us,
// FETCH 77MB, MfmaUtil 21.6%). Final ledger: gemm structural variants all
// worse (dbuf 92 / BK128 89.6 / 3-ring 90.2 / splitK 96.6 / K-rot 154.6 /
// fly-A 162.5 / BK128+remap 82.6) -> 64^2-tile 2-barrier compiler-scheduled
// loop + XCD-chunked remap is the local optimum. Time decomposition from
// R19's single-kernel bound: ~75us harness-fixed (reset dispatches) +
// prep ~32us (~18us roofline; "faster" preps R14/R15 measured slower e2e)
// + gemm 71us (latency/LDS-structural at 4.6 blocks/CU). 75+32+71 = 178 =
// measured. At the practical floor for this decomposition.

#define PDIM 33
#define PP   1089
#define A_   121
#define K_   3993
#define KP   4032
#define MP   1152            // padded M (18*64)
#define MT2  18              // M tiles (64)
#define NT2  66              // N tiles (64) = 33 i1 * 2 b-halves
#define NWG  1188            // MT2*NT2
#define OUTB 35937           // 33*33*33

typedef _Float16 f16x8 __attribute__((ext_vector_type(8)));
typedef float    f32x4 __attribute__((ext_vector_type(4)));
typedef _Float16 h2v   __attribute__((ext_vector_type(2)));

typedef __attribute__((address_space(1))) const unsigned int* gp_t;
typedef __attribute__((address_space(3))) unsigned int*       lp_t;

// ---------------- fused prep: Xt pack + W fill (R13 exact) ----------------

__global__ __launch_bounds__(256)
void prep_kernel(const float* __restrict__ x, const float* __restrict__ angles,
                 __half* __restrict__ Xt, __half* __restrict__ W)
{
    const int blk = blockIdx.x;
    const int t   = threadIdx.x;

    if (blk < PDIM * 128) {
        // ---- Xt row n=(i1*128+b): x[b,:,i1,:] flattened (j,k) fp16, K-pad 0.
        const int n  = blk;
        const int i1 = n >> 7;
        const int b  = n & 127;
        const float* src = x + (size_t)b * (A_ * PP) + (size_t)i1 * PDIM;
        unsigned int* dst = (unsigned int*)(Xt + (size_t)n * KP);
        for (int e = t; e < KP / 2; e += 256) {
            int kk0 = 2 * e, kk1 = 2 * e + 1;
            float v0 = 0.0f, v1 = 0.0f;
            if (kk0 < K_) {
                int j = kk0 / PDIM, k = kk0 - j * PDIM;
                v0 = src[(size_t)j * PP + k];
            }
            if (kk1 < K_) {
                int j = kk1 / PDIM, k = kk1 - j * PDIM;
                v1 = src[(size_t)j * PP + k];
            }
            dst[e] = __builtin_bit_cast(unsigned int,
                         __builtin_amdgcn_cvt_pkrtz(v0, v1));
        }
    } else {
        // ---- W row n: zero-fill (int4) then scatter the 2 bilinear taps/angle.
        const int n = blk - PDIM * 128;      // 0..1151
        __half* row = W + (size_t)n * KP;    // 8064 B, 16B-aligned
        int4 zz = make_int4(0, 0, 0, 0);
        for (int e = t; e < KP / 8; e += 256)
            ((int4*)row)[e] = zz;
        __syncthreads();
        if (n >= PP || t >= A_) return;
        const int j  = t;
        const int i0 = n / PDIM;
        const int i2 = n - i0 * PDIM;
        float s, c;
        sincosf(angles[j], &s, &c);
        float ix = fmaf((float)(i2 - 16), c, fmaf((float)(i0 - 16), s, 16.0f));
        float fl = floorf(ix);
        int   k0 = (int)fl;
        float w1 = ix - fl;
        float w0 = 1.0f - w1;
        __half* seg = row + j * PDIM;
        if (k0 >= 0     && k0 < PDIM)     seg[k0]     = __float2half_rn(w0);
        if (k0 + 1 >= 0 && k0 + 1 < PDIM) seg[k0 + 1] = __float2half_rn(w1);
    }
}

// GEMM: C = W . Xt^T, 64x64 tile, BK=64, 4 waves (2x2), 32x32 per wave.
// R9 2-barrier loop (compiler-scheduled) + XCD-chunked tile mapping.
__global__ __launch_bounds__(256)
void gemm_kernel(const __half* __restrict__ W, const __half* __restrict__ Xt,
                 float* __restrict__ out, float invA)
{
    __shared__ _Float16 As[64 * 64];     // 8 KB, chunk-swizzled
    __shared__ _Float16 Bs[64 * 64];     // 8 KB

    // ---- XCD-aware bijective remap (blk%8 = XCD; nwg=1188: q=148,r=4) ----
    // d = contiguous per-XCD work index; demand order = tileM-major within
    // 8 tileN-chunks of sizes {9,9,8,8,8,8,8,8} (chunk panels ~4.2MB ~ L2).
    const int b0  = blockIdx.x;
    const int xcd = b0 & 7;
    const int pos = b0 >> 3;
    const int d   = (xcd < 4) ? xcd * 149 + pos
                              : 596 + (xcd - 4) * 148 + pos;
    int tileM, tileN;
    if (d < 324) {                       // chunks 0,1: 9 panels each
        int c = d / 162, l = d - c * 162;
        tileM = l / 9;
        tileN = c * 9 + (l - tileM * 9);
    } else {                             // chunks 2..7: 8 panels each
        int dd = d - 324;
        int c = dd / 144, l = dd - c * 144;
        tileM = l >> 3;
        tileN = 18 + c * 8 + (l & 7);
    }

    const int t     = threadIdx.x;
    const int lane  = t & 63;
    const int wave  = t >> 6;
    const int warpM = wave >> 1;
    const int warpN = wave & 1;
    const int quad  = lane >> 4;
    const int l15   = lane & 15;

    f32x4 acc[2][2] = {};

    const __half* Ab = W  + (size_t)(tileM * 64) * KP;
    const __half* Bb = Xt + (size_t)(tileN * 64) * KP;

    // Staging chunk geometry: chunk cidx (0..511) = 16B = (row=cidx>>3,
    // seg=cidx&7). Global k-seg fetched = seg ^ (row&7); LDS dest linear.
    int srow[2], ssego[2];
#pragma unroll
    for (int i = 0; i < 2; ++i) {
        int cidx = t + i * 256;
        int row  = cidx >> 3;
        int seg  = cidx & 7;
        srow[i]  = row;
        ssego[i] = (seg ^ (row & 7)) * 8;   // halves offset within K-slice
    }

    // Frag-read addresses (halves): row r, k-seg ks -> r*64 + (ks^(r&7))*8
    int arow[2], brow[2];
#pragma unroll
    for (int s = 0; s < 2; ++s) {
        arow[s] = warpM * 32 + s * 16 + l15;
        brow[s] = warpN * 32 + s * 16 + l15;
    }

    for (int kb = 0; kb < KP; kb += 64) {
        __syncthreads();
#pragma unroll
        for (int i = 0; i < 2; ++i) {
            const __half* ga = Ab + (size_t)srow[i] * KP + kb + ssego[i];
            const __half* gb = Bb + (size_t)srow[i] * KP + kb + ssego[i];
            __builtin_amdgcn_global_load_lds((gp_t)(const void*)ga,
                (lp_t)(void*)&As[(t + i * 256) * 8], 16, 0, 0);
            __builtin_amdgcn_global_load_lds((gp_t)(const void*)gb,
                (lp_t)(void*)&Bs[(t + i * 256) * 8], 16, 0, 0);
        }
        __syncthreads();

        f16x8 af[2][2], bf[2][2];
#pragma unroll
        for (int h = 0; h < 2; ++h) {
#pragma unroll
            for (int s = 0; s < 2; ++s) {
                int ks = h * 4 + quad;
                af[h][s] = *(const f16x8*)&As[arow[s] * 64 + ((ks ^ (arow[s] & 7)) * 8)];
                bf[h][s] = *(const f16x8*)&Bs[brow[s] * 64 + ((ks ^ (brow[s] & 7)) * 8)];
            }
        }
#pragma unroll
        for (int h = 0; h < 2; ++h)
#pragma unroll
            for (int ms = 0; ms < 2; ++ms)
#pragma unroll
                for (int ns = 0; ns < 2; ++ns)
                    acc[ms][ns] = __builtin_amdgcn_mfma_f32_16x16x32_f16(
                        af[h][ms], bf[h][ns], acc[ms][ns], 0, 0, 0);
    }

    // Epilogue: C row m=(i0,i2), col nglob=(i1*128+b); out[b,i0,i1,i2].
#pragma unroll
    for (int ns = 0; ns < 2; ++ns) {
        int nglob = tileN * 64 + warpN * 32 + ns * 16 + l15;
        int i1 = nglob >> 7;
        int b  = nglob & 127;
        float* ob = out + (size_t)b * OUTB + (size_t)i1 * PDIM;
#pragma unroll
        for (int ms = 0; ms < 2; ++ms) {
#pragma unroll
            for (int r = 0; r < 4; ++r) {
                int m = tileM * 64 + warpM * 32 + ms * 16 + quad * 4 + r;
                if (m < PP) {
                    int i0 = m / PDIM;
                    int i2 = m - i0 * PDIM;
                    ob[(size_t)i0 * PP + i2] = acc[ms][ns][r] * invA;
                }
            }
        }
    }
}

// ---------------- fallback (R6, proven ~151 us) ----------------

#define ROWW 47
#define PADL 7
#define BLK  384
#define NV   3
#define GRID 1280

#if defined(__has_builtin)
#if __has_builtin(__builtin_amdgcn_fractf)
#define FRACTF(x) __builtin_amdgcn_fractf(x)
#endif
#endif
#ifndef FRACTF
#define FRACTF(x) ((x) - floorf(x))
#endif

__device__ __forceinline__ float fdot2u(unsigned int a, unsigned int b, float c)
{
    return __builtin_amdgcn_fdot2(__builtin_bit_cast(h2v, a),
                                  __builtin_bit_cast(h2v, b), c, false);
}

__global__ __launch_bounds__(BLK)
void fbp_adjoint_kernel(const float* __restrict__ x,
                        const float* __restrict__ angles,
                        float* __restrict__ out,
                        int nslice, float invA)
{
    __shared__ unsigned int dr[A_ * ROWW];
    __shared__ float2       cs_lds[A_];

    const int t = threadIdx.x;
    for (int j = t; j < A_; j += BLK) {
        float s, c;
        sincosf(angles[j], &s, &c);
        cs_lds[j] = make_float2(c, s);
    }

    float u0[NV], u2[NV];
#pragma unroll
    for (int nn = 0; nn < NV; ++nn) {
        int n  = t + nn * BLK;
        int nc = (n < PP) ? n : (PP - 1);
        int q0 = nc / PDIM;
        int q2 = nc - q0 * PDIM;
        u0[nn] = (float)(q0 - 16);
        u2[nn] = (float)(q2 - 16);
    }

    for (int slice = blockIdx.x; slice < nslice; slice += GRID) {
        if (slice != (int)blockIdx.x) __syncthreads();
        const int hb = slice / PDIM;
        const int i1 = slice - hb * PDIM;
        const int b0 = 2 * hb;
        const float* r0 = x + (size_t)b0 * (A_ * PP) + (size_t)i1 * PDIM;
        const float* r1 = r0 + (size_t)(A_ * PP);
        for (int e = t; e < A_ * ROWW; e += BLK) {
            int j = e / ROWW;
            int p = e - j * ROWW;
            int k = p - PADL;
            float f0 = 0.0f, f1 = 0.0f;
            if (k >= 0 && k < PDIM) {
                size_t o = (size_t)j * PP + k;
                f0 = r0[o];
                f1 = r1[o];
            }
            dr[e] = __builtin_bit_cast(unsigned int,
                        __halves2half2(__float2half_rn(f0), __float2half_rn(f1)));
        }
        __syncthreads();

        float a0[NV] = {0.0f, 0.0f, 0.0f};
        float a1[NV] = {0.0f, 0.0f, 0.0f};
#pragma unroll 2
        for (int j = 0; j < A_; ++j) {
            float2 cj = cs_lds[j];
            const unsigned int* base = &dr[j * ROWW];
#pragma unroll
            for (int nn = 0; nn < NV; ++nn) {
                float ixp = fmaf(u2[nn], cj.x, fmaf(u0[nn], cj.y, 23.0f));
                int   kp  = (int)ixp;
                float w1  = FRACTF(ixp);
                unsigned int wp = __builtin_bit_cast(unsigned int,
                                    __builtin_amdgcn_cvt_pkrtz(1.0f - w1, w1));
                unsigned int d0 = base[kp];
                unsigned int d1 = base[kp + 1];
                unsigned int p0 = __builtin_amdgcn_perm(d1, d0, 0x05040100u);
                unsigned int p1 = __builtin_amdgcn_perm(d1, d0, 0x07060302u);
                a0[nn] = fdot2u(p0, wp, a0[nn]);
                a1[nn] = fdot2u(p1, wp, a1[nn]);
            }
        }

        float* ob0 = out + (size_t)b0 * OUTB + (size_t)i1 * PDIM;
        float* ob1 = ob0 + (size_t)OUTB;
#pragma unroll
        for (int nn = 0; nn < NV; ++nn) {
            int n = t + nn * BLK;
            if (n < PP) {
                int q0 = n / PDIM;
                int q2 = n - q0 * PDIM;
                size_t o = (size_t)q0 * PP + q2;
                ob0[o] = a0[nn] * invA;
                ob1[o] = a1[nn] * invA;
            }
        }
    }
}

// ---------------- launch ----------------

extern "C" void kernel_launch(void* const* d_in, const int* in_sizes, int n_in,
                              void* d_out, int out_size, void* d_ws, size_t ws_size,
                              hipStream_t stream)
{
    const float* x      = (const float*)d_in[0];
    const float* angles = (const float*)d_in[1];
    float* out          = (float*)d_out;

    const int A = in_sizes[1];                    // 121
    const int B = in_sizes[0] / (A * PP);         // 128
    const float invA = 1.0f / (float)A;

    const size_t wBytes  = (size_t)MP * KP * sizeof(__half);         // 9.29 MB
    const size_t xtBytes = (size_t)(PDIM * B) * KP * sizeof(__half); // 34.1 MB

    if (ws_size >= wBytes + xtBytes && A == A_ && B == 128) {
        __half* W  = (__half*)d_ws;
        __half* Xt = (__half*)((char*)d_ws + wBytes);
        prep_kernel<<<PDIM * B + MP, 256, 0, stream>>>(x, angles, Xt, W);
        gemm_kernel<<<NWG, 256, 0, stream>>>(W, Xt, out, invA);
    } else {
        const int nslice = (B / 2) * PDIM;
        dim3 grid(GRID < nslice ? GRID : nslice);
        fbp_adjoint_kernel<<<grid, BLK, 0, stream>>>(x, angles, out,
                                                     nslice, invA);
    }
}